// Round 5
// baseline (517.899 us; speedup 1.0000x reference)
//
#include <hip/hip_runtime.h>
#include <cstdint>

// FracAttention: B=2, S=2048, D_MODEL=2048, H=16, DK=128
#define S_LEN   2048
#define DMODEL  2048
#define NHEADS  16
#define DK      128
#define MROWS   4096   // B*S
#define NKT     (DMODEL / 64)   // 32 K-tiles of BK=64

typedef _Float16 f16;
using f16x8 = __attribute__((ext_vector_type(8))) _Float16;
using f16x4 = __attribute__((ext_vector_type(4))) _Float16;
using f32x4 = __attribute__((ext_vector_type(4))) float;

typedef const __attribute__((address_space(1))) unsigned int gu32;
typedef __attribute__((address_space(3))) unsigned int lu32;

__device__ __forceinline__ void gl2lds16(const void* g, void* l) {
    // async global->LDS, 16 B per lane; LDS dest = wave-uniform base + lane*16
    __builtin_amdgcn_global_load_lds((gu32*)g, (lu32*)l, 16, 0, 0);
}

// ---------------------------------------------------------------------------
// fp32 -> fp16 convert, all 7 tensors in one dispatch (measured 60.5us).
// ---------------------------------------------------------------------------
__global__ __launch_bounds__(256) void cvt_all(
    const float* __restrict__ q, const float* __restrict__ k,
    const float* __restrict__ v, const float* __restrict__ wq,
    const float* __restrict__ wk, const float* __restrict__ wv,
    const float* __restrict__ wo,
    f16* cq, f16* ck, f16* cv, f16* cwq, f16* cwk, f16* cwv, f16* cwo)
{
    const int b = blockIdx.x;
    const float* src; f16* dst; int base;
    if      (b <  8192) { src = q;  dst = cq;  base = b; }
    else if (b < 16384) { src = k;  dst = ck;  base = b - 8192; }
    else if (b < 24576) { src = v;  dst = cv;  base = b - 16384; }
    else if (b < 28672) { src = wq; dst = cwq; base = b - 24576; }
    else if (b < 32768) { src = wk; dst = cwk; base = b - 28672; }
    else if (b < 36864) { src = wv; dst = cwv; base = b - 32768; }
    else                { src = wo; dst = cwo; base = b - 36864; }
    const int i = base * 256 + threadIdx.x;
    float4 x = ((const float4*)src)[i];
    f16x4 o; o[0] = (f16)x.x; o[1] = (f16)x.y; o[2] = (f16)x.z; o[3] = (f16)x.w;
    ((f16x4*)dst)[i] = o;
}

// ---------------------------------------------------------------------------
// fp16 MFMA GEMM, m201 8-phase port: C[M][N] = A[M][K] @ W[N][K]^T + bias.
// BM=256, BK=64, 512 threads = 8 waves (2Mx4N), per-wave 128 x (BN/4).
// LDS = 2 dbuf x 2 k-half x {A 256x32, B} (128 KB BN=256 / 96 KB BN=128).
// 4 phases per K-tile; each phase: {ds_read 4-8 b128 | stage 2 gl2lds |
// s_barrier | lgkmcnt(0)+sched_barrier | setprio(1) 16(8) MFMA setprio(0) |
// s_barrier}. Counted vmcnt at p1/p3 ends only (FIFO-derived: vmcnt(4)
// retires exactly the k-half about to be consumed; never 0 until the final
// k-half). T2 XOR swizzle on all LDS reads (verified: conflicts -> 0).
// T1 XCD-chunked block swizzle applied by callers.
// Aliasing rule (round-2 post-mortem): outputs never alias same-launch
// inputs (Kh/VT live in d_out).
// mode 0: fp32 out [M][N]
// mode 1: f16 out head-permuted [B,H,S,DK]              (K)
// mode 2: f16 out head-permuted + transposed [B,H,DK,S] (V -> VT)
// mode 3: f16 out head-permuted, scaled by sa[h]/max(sb[h],1) (Q)
// ---------------------------------------------------------------------------
template<int BN>
__device__ __forceinline__ void gemm8(
    const f16* __restrict__ A, const f16* __restrict__ W,
    const float* __restrict__ bias, void* __restrict__ Cout,
    int mode, const float* __restrict__ sa, const float* __restrict__ sb,
    int bx, int by)
{
    constexpr int NJ = BN / 64;                 // 4 (qkv) or 2 (out)
    __shared__ f16 As[4 * 8192];                // [d][kh][256 rows][32]
    __shared__ f16 Bs[(BN == 256 ? 4 : 2) * 8192];

    const int tid  = threadIdx.x;
    const int wid  = tid >> 6;
    const int ln   = tid & 15;
    const int quad = (tid & 63) >> 4;
    const int wm   = (wid >> 2) * 128;
    const int wn   = (wid & 3) * (16 * NJ);
    const int bm   = by * 256;
    const int bn   = bx * BN;
    const int K    = DMODEL;

    f32x4 acc[8][NJ];
#pragma unroll
    for (int i = 0; i < 8; ++i)
#pragma unroll
        for (int j = 0; j < NJ; ++j)
            acc[i][j] = (f32x4){0.f, 0.f, 0.f, 0.f};

    // T2 swizzle: read chunk = quad ^ ((row>>1)&3) (A / B256, 32-f16 rows);
    // B128 rows are 64 f16 -> 8 chunks, key row&7. Staging pre-swizzles the
    // global source chunk with the same involution; gl2lds dest stays linear.
    const int koff = (quad ^ ((ln >> 1) & 3)) * 8;
    const int kcs4 = ((tid & 3) ^ ((tid >> 3) & 3)) * 8;
    const int kcs8 = ((tid & 7) ^ ((tid >> 3) & 7)) * 8;
    const f16* gA = A + (size_t)(bm + (tid >> 2)) * K + kcs4;
    const f16* gB = (BN == 256)
        ? W + (size_t)(bn + (tid >> 2)) * K + kcs4
        : W + (size_t)(bn + (tid >> 3)) * K + kcs8;

#define SA_(t_, kh_) do { \
    f16* dst_ = &As[(((t_) & 1) * 2 + (kh_)) * 8192]; \
    const f16* g_ = gA + (t_) * 64 + (kh_) * 32; \
    gl2lds16(g_,                   dst_ + tid * 8); \
    gl2lds16(g_ + (size_t)128 * K, dst_ + (tid + 512) * 8); } while (0)

#define SB256_(t_, kh_) do { \
    f16* dst_ = &Bs[(((t_) & 1) * 2 + (kh_)) * 8192]; \
    const f16* g_ = gB + (t_) * 64 + (kh_) * 32; \
    gl2lds16(g_,                   dst_ + tid * 8); \
    gl2lds16(g_ + (size_t)128 * K, dst_ + (tid + 512) * 8); } while (0)

#define SB128_(t_) do { \
    f16* dst_ = &Bs[((t_) & 1) * 8192]; \
    const f16* g_ = gB + (t_) * 64; \
    gl2lds16(g_,                  dst_ + tid * 8); \
    gl2lds16(g_ + (size_t)64 * K, dst_ + (tid + 512) * 8); } while (0)

#define LDA_(d_, kh_, R_) do { \
    const f16* p_ = &As[((d_) * 2 + (kh_)) * 8192]; \
    _Pragma("unroll") \
    for (int i_ = 0; i_ < 4; ++i_) \
        af[i_] = *(const f16x8*)&p_[(wm + ((R_) + i_) * 16 + ln) * 32 + koff]; \
    } while (0)

#define LDB_(d_, kh_) do { \
    if constexpr (BN == 256) { \
        const f16* p_ = &Bs[((d_) * 2 + (kh_)) * 8192]; \
        _Pragma("unroll") \
        for (int j_ = 0; j_ < NJ; ++j_) \
            bf[j_] = *(const f16x8*)&p_[(wn + j_ * 16 + ln) * 32 + koff]; \
    } else { \
        const f16* p_ = &Bs[(d_) * 8192]; \
        _Pragma("unroll") \
        for (int j_ = 0; j_ < NJ; ++j_) \
            bf[j_] = *(const f16x8*)&p_[(wn + j_ * 16 + ln) * 64 \
                         + ((((kh_) * 4 + quad) ^ (ln & 7)) * 8)]; \
    } } while (0)

#define MF_(R_) do { \
    __builtin_amdgcn_s_setprio(1); \
    _Pragma("unroll") \
    for (int i_ = 0; i_ < 4; ++i_) \
    _Pragma("unroll") \
        for (int j_ = 0; j_ < NJ; ++j_) \
            acc[(R_) + i_][j_] = __builtin_amdgcn_mfma_f32_16x16x32_f16( \
                af[i_], bf[j_], acc[(R_) + i_][j_], 0, 0, 0); \
    __builtin_amdgcn_s_setprio(0); } while (0)

#define BAR_  __builtin_amdgcn_s_barrier()
#define SBAR_ __builtin_amdgcn_sched_barrier(0)
#define LGKM0_ do { asm volatile("s_waitcnt lgkmcnt(0)" ::: "memory"); SBAR_; } while (0)

    // prologue: stage tile 0 in canonical issue order [A-kh0, B(-kh0), A-kh1, (B-kh1)]
    SA_(0, 0);
    if constexpr (BN == 256) SB256_(0, 0); else SB128_(0);
    SA_(0, 1);
    if constexpr (BN == 256) SB256_(0, 1);
    if constexpr (BN == 256) asm volatile("s_waitcnt vmcnt(4)" ::: "memory");
    else                     asm volatile("s_waitcnt vmcnt(2)" ::: "memory");
    BAR_; SBAR_;

    for (int t = 0; t < NKT; ++t) {
        const int d = t & 1;
        const bool nl = (t + 1 < NKT);
        f16x8 af[4], bf[NJ];

        // ---- p0: kh0, frag rows 0-3 ----
        LDB_(d, 0); LDA_(d, 0, 0);
        if (nl) SA_(t + 1, 0);
        BAR_; LGKM0_; MF_(0);
        BAR_;

        // ---- p1: kh0, frag rows 4-7 ----
        LDA_(d, 0, 4);
        if (nl) { if constexpr (BN == 256) SB256_(t + 1, 0); else SB128_(t + 1); }
        BAR_; LGKM0_; MF_(4);
        if (nl) asm volatile("s_waitcnt vmcnt(4)" ::: "memory");   // retire kh1(t)
        else    asm volatile("s_waitcnt vmcnt(0)" ::: "memory");
        BAR_; SBAR_;

        // ---- p2: kh1, frag rows 0-3 ----
        LDB_(d, 1); LDA_(d, 1, 0);
        if (nl) SA_(t + 1, 1);
        BAR_; LGKM0_; MF_(0);
        BAR_;

        // ---- p3: kh1, frag rows 4-7 ----
        LDA_(d, 1, 4);
        if (nl) { if constexpr (BN == 256) SB256_(t + 1, 1); }
        BAR_; LGKM0_; MF_(4);
        if (nl) {                                                  // retire kh0(t+1)
            if constexpr (BN == 256) asm volatile("s_waitcnt vmcnt(4)" ::: "memory");
            else                     asm volatile("s_waitcnt vmcnt(2)" ::: "memory");
        }
        BAR_; SBAR_;
    }

#undef SA_
#undef SB256_
#undef SB128_
#undef LDA_
#undef LDB_
#undef MF_
#undef BAR_
#undef SBAR_
#undef LGKM0_

    // epilogue: C/D layout col=lane&15, row=quad*4+reg
    const int N = DMODEL;
#pragma unroll
    for (int j = 0; j < NJ; ++j) {
        const int n = bn + wn + j * 16 + ln;
        const float bn_ = bias[n];
        const int h = n >> 7;           // n / DK
        const int dd = n & (DK - 1);
        float scq = 1.0f;
        if (mode == 3) scq = sa[h] / fmaxf(sb[h], 1.0f);
#pragma unroll
        for (int i = 0; i < 8; ++i) {
#pragma unroll
            for (int reg = 0; reg < 4; ++reg) {
                const int m = bm + wm + i * 16 + quad * 4 + reg;
                float v = acc[i][j][reg] + bn_;
                if (mode == 0) {
                    ((float*)Cout)[(size_t)m * N + n] = v;
                } else {
                    const int bb = m >> 11;          // / S_LEN
                    const int ss = m & (S_LEN - 1);
                    size_t idx;
                    if (mode == 2)
                        idx = (((size_t)(bb * NHEADS + h) * DK + dd) * S_LEN + ss);
                    else
                        idx = (((size_t)(bb * NHEADS + h) * S_LEN + ss) * DK + dd);
                    if (mode == 3) v *= scq;
                    ((f16*)Cout)[idx] = (f16)v;
                }
            }
        }
    }
}

__global__ __launch_bounds__(512, 2) void qkv_gemm(
    const f16* Aq, const f16* Ak, const f16* Av,
    const f16* Wq, const f16* Wk, const f16* Wv,
    const float* bq, const float* bk, const float* bv,
    f16* Oq, f16* Ok, f16* Ov, const float* sa, const float* sb)
{
    // T1 XCD-chunked swizzle: 384 blocks, 48 consecutive tiles per XCD
    const int lin = blockIdx.x + (blockIdx.y << 3) + (blockIdx.z << 7);
    const int swz = (lin & 7) * 48 + (lin >> 3);
    const int bx = swz & 7, by = (swz >> 3) & 15, z = swz >> 7;

    const f16* A = (z == 0) ? Aq : (z == 1) ? Ak : Av;
    const f16* W = (z == 0) ? Wq : (z == 1) ? Wk : Wv;
    const float* bias = (z == 0) ? bq : (z == 1) ? bk : bv;
    void* O = (z == 0) ? (void*)Oq : (z == 1) ? (void*)Ok : (void*)Ov;
    const int mode = (z == 0) ? 3 : (z == 1) ? 1 : 2;
    gemm8<256>(A, W, bias, O, mode, sa, sb, bx, by);
}

__global__ __launch_bounds__(512, 2) void out_gemm(
    const f16* A, const f16* W, const float* bias, float* O)
{
    // 256 blocks = exactly 1/CU, one even round; T1 chunked swizzle (32/XCD)
    const int lin = blockIdx.x + (blockIdx.y << 4);
    const int swz = (lin & 7) * 32 + (lin >> 3);
    const int bx = swz & 15, by = swz >> 4;
    gemm8<128>(A, W, bias, O, 0, nullptr, nullptr, bx, by);
}

// ---------------------------------------------------------------------------
// Flash attention v5 (unchanged this round, for attribution): fp16 MFMA,
// reduction-free softmax, T2 swizzle on Ks/Vs/Ps, setprio on MFMA clusters.
// ---------------------------------------------------------------------------
__global__ __launch_bounds__(256, 2) void flash_v4(
    const f16* __restrict__ Qg, const f16* __restrict__ Kg,
    const f16* __restrict__ VTg, f16* __restrict__ AO)
{
    __shared__ f16 Ks[4 * 64 * 32];    // [kc][c][32]
    __shared__ f16 Vs[2 * 128 * 32];   // [cc][d][32]
    __shared__ f16 Ps[2 * 128 * 32];   // [cc][q][32]
    __shared__ float l_buf[2 * 128];   // [wc][q]

    const int tid = threadIdx.x;
    const int wid = tid >> 6;
    const int ln = tid & 15;
    const int quad = (tid & 63) >> 4;
    const int wq = wid & 1;
    const int wc = wid >> 1;
    const int bh = blockIdx.y;
    const int q0 = blockIdx.x * 128;

    const int koff = (quad ^ ((ln >> 1) & 3)) * 8;                 // read, b128
    const int soff_sw = ((tid & 3) ^ ((tid >> 3) & 3)) * 8;        // staging src

    f16x8 qf[4][4];
    const f16* Qbase = Qg + ((size_t)bh * S_LEN + q0 + wq * 64) * DK;
#pragma unroll
    for (int nt = 0; nt < 4; ++nt)
#pragma unroll
        for (int kc = 0; kc < 4; ++kc)
            qf[nt][kc] = *(const f16x8*)(Qbase + (size_t)(nt * 16 + ln) * DK
                                         + kc * 32 + quad * 8);

    f32x4 o[4][4];
    float lp[4] = {0.f, 0.f, 0.f, 0.f};
#pragma unroll
    for (int i = 0; i < 4; ++i)
#pragma unroll
        for (int j = 0; j < 4; ++j)
            o[i][j] = (f32x4){0.f, 0.f, 0.f, 0.f};

    const f16* Kgb = Kg + (size_t)bh * S_LEN * DK;
    const f16* Vgb = VTg + (size_t)bh * DK * S_LEN;
    const int srow = tid >> 2;

    for (int kt = 0; kt < S_LEN / 64; ++kt) {
        __syncthreads();
#pragma unroll
        for (int j = 0; j < 4; ++j)
            gl2lds16(Kgb + (size_t)(kt * 64 + srow) * DK + j * 32 + soff_sw,
                     Ks + j * 2048 + tid * 8);
#pragma unroll
        for (int j = 0; j < 4; ++j)
            gl2lds16(Vgb + (size_t)(srow + (j & 1) * 64) * S_LEN
                         + kt * 64 + (j >> 1) * 32 + soff_sw,
                     Vs + (j >> 1) * 4096 + (j & 1) * 2048 + tid * 8);
        __syncthreads();

        f32x4 s[2][4];
#pragma unroll
        for (int mt = 0; mt < 2; ++mt)
#pragma unroll
            for (int nt = 0; nt < 4; ++nt)
                s[mt][nt] = (f32x4){0.f, 0.f, 0.f, 0.f};
        __builtin_amdgcn_s_setprio(1);
#pragma unroll
        for (int kc = 0; kc < 4; ++kc) {
            f16x8 kf0 = *(const f16x8*)&Ks[kc * 2048 + (wc * 32 + ln) * 32 + koff];
            f16x8 kf1 = *(const f16x8*)&Ks[kc * 2048 + (wc * 32 + 16 + ln) * 32 + koff];
#pragma unroll
            for (int nt = 0; nt < 4; ++nt) {
                s[0][nt] = __builtin_amdgcn_mfma_f32_16x16x32_f16(kf0, qf[nt][kc], s[0][nt], 0, 0, 0);
                s[1][nt] = __builtin_amdgcn_mfma_f32_16x16x32_f16(kf1, qf[nt][kc], s[1][nt], 0, 0, 0);
            }
        }
        __builtin_amdgcn_s_setprio(0);

#pragma unroll
        for (int mt = 0; mt < 2; ++mt) {
#pragma unroll
            for (int nt = 0; nt < 4; ++nt) {
                const float p0 = __expf(s[mt][nt][0]);
                const float p1 = __expf(s[mt][nt][1]);
                const float p2 = __expf(s[mt][nt][2]);
                const float p3 = __expf(s[mt][nt][3]);
                lp[nt] += (p0 + p1) + (p2 + p3);
                f16x4 pk;
                pk[0] = (f16)p0; pk[1] = (f16)p1; pk[2] = (f16)p2; pk[3] = (f16)p3;
                const int pchunk = ((mt * 2 + (quad >> 1)) ^ ((ln >> 1) & 3)) * 8
                                   + (quad & 1) * 4;
                *(f16x4*)&Ps[wc * 4096 + (wq * 64 + nt * 16 + ln) * 32 + pchunk] = pk;
            }
        }
        __syncthreads();

        __builtin_amdgcn_s_setprio(1);
#pragma unroll
        for (int cc = 0; cc < 2; ++cc) {
            f16x8 pf[4];
#pragma unroll
            for (int mtq = 0; mtq < 4; ++mtq)
                pf[mtq] = *(const f16x8*)&Ps[cc * 4096 + (wq * 64 + mtq * 16 + ln) * 32 + koff];
#pragma unroll
            for (int ntd = 0; ntd < 4; ++ntd) {
                f16x8 vf = *(const f16x8*)&Vs[cc * 4096 + (wc * 64 + ntd * 16 + ln) * 32 + koff];
#pragma unroll
                for (int mtq = 0; mtq < 4; ++mtq)
                    o[mtq][ntd] = __builtin_amdgcn_mfma_f32_16x16x32_f16(
                        pf[mtq], vf, o[mtq][ntd], 0, 0, 0);
            }
        }
        __builtin_amdgcn_s_setprio(0);
    }

#pragma unroll
    for (int nt = 0; nt < 4; ++nt) {
        float v = lp[nt];
        v += __shfl_xor(v, 16, 64);
        v += __shfl_xor(v, 32, 64);
        lp[nt] = v;
    }
    if (quad == 0) {
#pragma unroll
        for (int nt = 0; nt < 4; ++nt)
            l_buf[wc * 128 + wq * 64 + nt * 16 + ln] = lp[nt];
    }
    __syncthreads();

    const int b = bh >> 4;
    const int h = bh & (NHEADS - 1);
#pragma unroll
    for (int mtq = 0; mtq < 4; ++mtq) {
#pragma unroll
        for (int reg = 0; reg < 4; ++reg) {
            const int ql = wq * 64 + mtq * 16 + quad * 4 + reg;
            const float inv = 1.0f / (l_buf[ql] + l_buf[128 + ql]);
            f16* dst = AO + ((size_t)b * S_LEN + q0 + ql) * DMODEL + h * DK + wc * 64;
#pragma unroll
            for (int ntd = 0; ntd < 4; ++ntd)
                dst[ntd * 16 + ln] = (f16)(o[mtq][ntd][reg] * inv);
        }
    }
}

// ---------------------------------------------------------------------------
// Buffer plan (race-free): Kh/VT in d_out (dead until out_gemm, which fully
// overwrites it after flash consumed Kh/VT); AOh aliases c_v (cross-launch).
// No output of any launch aliases an input of the SAME launch.
// ---------------------------------------------------------------------------
extern "C" void kernel_launch(void* const* d_in, const int* in_sizes, int n_in,
                              void* d_out, int out_size, void* d_ws, size_t ws_size,
                              hipStream_t stream)
{
    (void)in_sizes; (void)n_in; (void)out_size; (void)ws_size;
    const float* query = (const float*)d_in[0];
    const float* key_  = (const float*)d_in[1];
    const float* value = (const float*)d_in[2];
    const float* w_q = (const float*)d_in[3];
    const float* b_q = (const float*)d_in[4];
    const float* w_k = (const float*)d_in[5];
    const float* b_k = (const float*)d_in[6];
    const float* w_v = (const float*)d_in[7];
    const float* b_v = (const float*)d_in[8];
    const float* w_o = (const float*)d_in[9];
    const float* b_o = (const float*)d_in[10];
    const float* s_alpha = (const float*)d_in[11];
    const float* s_beta  = (const float*)d_in[12];
    float* out = (float*)d_out;

    const size_t T = (size_t)MROWS * DMODEL;    // 8,388,608
    const size_t Wn = (size_t)DMODEL * DMODEL;  // 4,194,304
    f16* base = (f16*)d_ws;
    f16* c_q = base;
    f16* c_k = base + T;
    f16* c_v = base + 2 * T;      // later reused as AOh (cross-launch, safe)
    f16* Qh  = base + 3 * T;
    f16* wq16 = base + 4 * T;
    f16* wk16 = wq16 + Wn;
    f16* wv16 = wk16 + Wn;
    f16* wo16 = wv16 + Wn;
    f16* Kh  = (f16*)d_out;       // 16MB: first half of d_out
    f16* VT  = Kh + T;            // 16MB: second half of d_out
    f16* AOh = c_v;

    cvt_all<<<dim3(40960), dim3(256), 0, stream>>>(
        query, key_, value, w_q, w_k, w_v, w_o,
        c_q, c_k, c_v, wq16, wk16, wv16, wo16);

    dim3 qkv_grid(DMODEL / 256, MROWS / 256, 3);  // (8, 16, 3) = 384 blocks
    qkv_gemm<<<qkv_grid, dim3(512), 0, stream>>>(c_q, c_k, c_v, wq16, wk16, wv16,
                                                 b_q, b_k, b_v, Qh, Kh, VT,
                                                 s_alpha, s_beta);

    dim3 flash_grid(S_LEN / 128, 2 * NHEADS);     // (16, 32)
    flash_v4<<<flash_grid, dim3(256), 0, stream>>>(Qh, Kh, VT, AOh);

    dim3 out_grid(DMODEL / 128, MROWS / 256);     // (16, 16) = 256 blocks
    out_gemm<<<out_grid, dim3(512), 0, stream>>>(AOh, wo16, b_o, out);
}

// Round 6
// 460.351 us; speedup vs baseline: 1.1250x; 1.1250x over previous
//
#include <hip/hip_runtime.h>
#include <cstdint>

// FracAttention: B=2, S=2048, D_MODEL=2048, H=16, DK=128
#define S_LEN   2048
#define DMODEL  2048
#define NHEADS  16
#define DK      128
#define MROWS   4096   // B*S

typedef _Float16 f16;
using f16x8 = __attribute__((ext_vector_type(8))) _Float16;
using f16x4 = __attribute__((ext_vector_type(4))) _Float16;
using f32x4 = __attribute__((ext_vector_type(4))) float;

typedef const __attribute__((address_space(1))) unsigned int gu32;
typedef __attribute__((address_space(3))) unsigned int lu32;

__device__ __forceinline__ void gl2lds16(const void* g, void* l) {
    // async global->LDS, 16 B per lane; LDS dest = wave-uniform base + lane*16
    __builtin_amdgcn_global_load_lds((gu32*)g, (lu32*)l, 16, 0, 0);
}

// ---------------------------------------------------------------------------
// fp32 -> fp16 convert. 4 float4 per thread (64 B/lane), 10240 blocks
// (was 40960 1-float4 blocks at 34% HBM -- dispatch-bound).
// ---------------------------------------------------------------------------
__global__ __launch_bounds__(256) void cvt_all(
    const float* __restrict__ q, const float* __restrict__ k,
    const float* __restrict__ v, const float* __restrict__ wq,
    const float* __restrict__ wk, const float* __restrict__ wv,
    const float* __restrict__ wo,
    f16* cq, f16* ck, f16* cv, f16* cwq, f16* cwk, f16* cwv, f16* cwo)
{
    const int b = blockIdx.x;
    const float* src; f16* dst; int base;
    if      (b <  2048) { src = q;  dst = cq;  base = b; }
    else if (b <  4096) { src = k;  dst = ck;  base = b - 2048; }
    else if (b <  6144) { src = v;  dst = cv;  base = b - 4096; }
    else if (b <  7168) { src = wq; dst = cwq; base = b - 6144; }
    else if (b <  8192) { src = wk; dst = cwk; base = b - 7168; }
    else if (b <  9216) { src = wv; dst = cwv; base = b - 8192; }
    else                { src = wo; dst = cwo; base = b - 9216; }
    const int i = base * 1024 + threadIdx.x;
#pragma unroll
    for (int u = 0; u < 4; ++u) {
        float4 x = ((const float4*)src)[i + u * 256];
        f16x4 o; o[0] = (f16)x.x; o[1] = (f16)x.y; o[2] = (f16)x.z; o[3] = (f16)x.w;
        ((f16x4*)dst)[i + u * 256] = o;
    }
}

// ---------------------------------------------------------------------------
// fp16 MFMA GEMM core: C[M][N] = A[M][K] @ W[N][K]^T + bias
// BYTE-EXACT revert to the round-0 measured-best structure (151.6/53.5 us):
// 128x128 tile, BK=32, 256 threads, 2x2 waves, 4x4 16x16x32 frags/wave,
// 2 barriers per K-tile, gl2lds staging, high occupancy (16 KB LDS, 80 VGPR,
// 4-6 blocks/CU -> implicit wave-level overlap per m114). Three deeper
// pipelined variants (r1/r4/r5) all measured equal or worse.
// mode 0: fp32 out [M][N]
// mode 1: f16 out head-permuted  [B,H,S,DK]             (K)
// mode 2: f16 out head-permuted + transposed [B,H,DK,S] (V -> VT)
// mode 3: f16 out head-permuted, scaled by sa[h]/max(sb[h],1)  (Q)
// ---------------------------------------------------------------------------
__device__ __forceinline__ void gemm_core(
    const f16* __restrict__ A, const f16* __restrict__ W,
    const float* __restrict__ bias, void* __restrict__ Cout,
    int mode, const float* __restrict__ sa, const float* __restrict__ sb)
{
    __shared__ f16 As[128 * 32];   // [m][k-chunk of 32]
    __shared__ f16 Bs[128 * 32];   // [n][k-chunk of 32]

    const int tid = threadIdx.x;
    const int bm = blockIdx.y * 128;
    const int bn = blockIdx.x * 128;
    const int wid = tid >> 6;
    const int ln = tid & 15;
    const int quad = (tid & 63) >> 4;
    const int wm = (wid >> 1) * 64;
    const int wn = (wid & 1) * 64;
    const int K = DMODEL, N = DMODEL;

    f32x4 acc[4][4];
#pragma unroll
    for (int i = 0; i < 4; ++i)
#pragma unroll
        for (int j = 0; j < 4; ++j)
            acc[i][j] = (f32x4){0.f, 0.f, 0.f, 0.f};

    const int sr = tid >> 2;
    const int ke = (tid & 3) * 8;
    const f16* ga0 = A + (size_t)(bm + sr) * K + ke;
    const f16* ga1 = A + (size_t)(bm + 64 + sr) * K + ke;
    const f16* gb0 = W + (size_t)(bn + sr) * K + ke;
    const f16* gb1 = W + (size_t)(bn + 64 + sr) * K + ke;
    f16* la0 = As + tid * 8;
    f16* la1 = As + 2048 + tid * 8;
    f16* lb0 = Bs + tid * 8;
    f16* lb1 = Bs + 2048 + tid * 8;

    for (int k0 = 0; k0 < K; k0 += 32) {
        __syncthreads();
        gl2lds16(ga0 + k0, la0);
        gl2lds16(ga1 + k0, la1);
        gl2lds16(gb0 + k0, lb0);
        gl2lds16(gb1 + k0, lb1);
        __syncthreads();

        f16x8 af[4], bf[4];
#pragma unroll
        for (int i = 0; i < 4; ++i)
            af[i] = *(const f16x8*)&As[(wm + i * 16 + ln) * 32 + quad * 8];
#pragma unroll
        for (int j = 0; j < 4; ++j)
            bf[j] = *(const f16x8*)&Bs[(wn + j * 16 + ln) * 32 + quad * 8];
#pragma unroll
        for (int i = 0; i < 4; ++i)
#pragma unroll
            for (int j = 0; j < 4; ++j)
                acc[i][j] = __builtin_amdgcn_mfma_f32_16x16x32_f16(
                    af[i], bf[j], acc[i][j], 0, 0, 0);
    }

    // epilogue: C/D layout col=lane&15, row=quad*4+reg
#pragma unroll
    for (int j = 0; j < 4; ++j) {
        const int n = bn + wn + j * 16 + ln;
        const float bn_ = bias[n];
        const int h = n >> 7;           // n / DK
        const int d = n & (DK - 1);
        float scq = 1.0f;
        if (mode == 3) scq = sa[h] / fmaxf(sb[h], 1.0f);
#pragma unroll
        for (int i = 0; i < 4; ++i) {
#pragma unroll
            for (int reg = 0; reg < 4; ++reg) {
                const int m = bm + wm + i * 16 + quad * 4 + reg;
                float v = acc[i][j][reg] + bn_;
                if (mode == 0) {
                    ((float*)Cout)[(size_t)m * N + n] = v;
                } else {
                    const int bb = m >> 11;          // / S_LEN
                    const int ss = m & (S_LEN - 1);
                    size_t idx;
                    if (mode == 2)
                        idx = (((size_t)(bb * NHEADS + h) * DK + d) * S_LEN + ss);
                    else
                        idx = (((size_t)(bb * NHEADS + h) * S_LEN + ss) * DK + d);
                    if (mode == 3) v *= scq;
                    ((f16*)Cout)[idx] = (f16)v;
                }
            }
        }
    }
}

__global__ __launch_bounds__(256) void qkv_gemm(
    const f16* Aq, const f16* Ak, const f16* Av,
    const f16* Wq, const f16* Wk, const f16* Wv,
    const float* bq, const float* bk, const float* bv,
    f16* Oq, f16* Ok, f16* Ov, const float* sa, const float* sb)
{
    const int z = blockIdx.z;
    const f16* A = (z == 0) ? Aq : (z == 1) ? Ak : Av;
    const f16* W = (z == 0) ? Wq : (z == 1) ? Wk : Wv;
    const float* bias = (z == 0) ? bq : (z == 1) ? bk : bv;
    void* O = (z == 0) ? (void*)Oq : (z == 1) ? (void*)Ok : (void*)Ov;
    const int mode = (z == 0) ? 3 : (z == 1) ? 1 : 2;
    gemm_core(A, W, bias, O, mode, sa, sb);
}

__global__ __launch_bounds__(256) void out_gemm(
    const f16* A, const f16* W, const float* bias, float* O)
{
    gemm_core(A, W, bias, O, 0, nullptr, nullptr);
}

// ---------------------------------------------------------------------------
// Flash attention v6: K double-buffered + counted-vmcnt pipeline.
// Old structure drained vmcnt(0) via __syncthreads with ZERO compute between
// staging issue and drain, 32x per block. New per-iter schedule:
//   [lgkm0+bar]  issue V(kt)                (V latency hides under QK^T)
//   vmcnt(4) -> K(kt) ready   [bar]
//   QK^T(kt) from Ks[kt&1]; issue K(kt+1) -> Ks[(kt+1)&1]  (other buffer)
//   exp + P-writes; vmcnt(4) -> V(kt) ready  (K(kt+1) stays in flight)
//   [lgkm0+bar]  PV(kt)
// K(kt+1) rides across ALL barriers (counted waits only, T4).
// LDS 65 KB -> still 2 blocks/CU. T2 swizzles + setprio kept (refcheck'd).
// XCD bh-chunk swizzle: 4 consecutive bh (= 4 MB K/V = one L2) per XCD.
// ---------------------------------------------------------------------------
__global__ __launch_bounds__(256, 2) void flash_v6(
    const f16* __restrict__ Qg, const f16* __restrict__ Kg,
    const f16* __restrict__ VTg, f16* __restrict__ AO)
{
    __shared__ f16 Ks[2][4 * 64 * 32];  // dbuf: [kb][kc][c][32]  32 KB
    __shared__ f16 Vs[2 * 128 * 32];    // [cc][d][32]            16 KB
    __shared__ f16 Ps[2 * 128 * 32];    // [cc][q][32]            16 KB
    __shared__ float l_buf[2 * 128];    // [wc][q]                 1 KB

    const int tid = threadIdx.x;
    const int wid = tid >> 6;
    const int ln = tid & 15;
    const int quad = (tid & 63) >> 4;
    const int wq = wid & 1;
    const int wc = wid >> 1;

    // XCD chunk swizzle: lin -> (bh-chunk per XCD); 512 blocks, 64/XCD.
    const int lin = blockIdx.x + (blockIdx.y << 4);
    const int swz = (lin & 7) * 64 + (lin >> 3);
    const int q0 = (swz & 15) * 128;
    const int bh = swz >> 4;

    const int koff = (quad ^ ((ln >> 1) & 3)) * 8;                 // read, b128
    const int soff_sw = ((tid & 3) ^ ((tid >> 3) & 3)) * 8;        // staging src

    // Q fragments to registers (wave's 64 q-rows, pre-scaled)
    f16x8 qf[4][4];
    const f16* Qbase = Qg + ((size_t)bh * S_LEN + q0 + wq * 64) * DK;
#pragma unroll
    for (int nt = 0; nt < 4; ++nt)
#pragma unroll
        for (int kc = 0; kc < 4; ++kc)
            qf[nt][kc] = *(const f16x8*)(Qbase + (size_t)(nt * 16 + ln) * DK
                                         + kc * 32 + quad * 8);

    f32x4 o[4][4];
    float lp[4] = {0.f, 0.f, 0.f, 0.f};
#pragma unroll
    for (int i = 0; i < 4; ++i)
#pragma unroll
        for (int j = 0; j < 4; ++j)
            o[i][j] = (f32x4){0.f, 0.f, 0.f, 0.f};

    const f16* Kgb = Kg + (size_t)bh * S_LEN * DK;
    const f16* Vgb = VTg + (size_t)bh * DK * S_LEN;
    const int srow = tid >> 2;

    // prologue: stage K(0) into Ks[0]
#pragma unroll
    for (int j = 0; j < 4; ++j)
        gl2lds16(Kgb + (size_t)(srow)*DK + j * 32 + soff_sw,
                 &Ks[0][j * 2048 + tid * 8]);

    for (int kt = 0; kt < S_LEN / 64; ++kt) {
        // loop top: PV(kt-1) ds_reads retired everywhere -> Vs/Ps writable.
        // (lgkm only -- K(kt) vmem prefetch stays in flight)
        asm volatile("s_waitcnt lgkmcnt(0)" ::: "memory");
        __builtin_amdgcn_s_barrier();
        __builtin_amdgcn_sched_barrier(0);

        // issue V(kt)
#pragma unroll
        for (int j = 0; j < 4; ++j)
            gl2lds16(Vgb + (size_t)(srow + (j & 1) * 64) * S_LEN
                         + kt * 64 + (j >> 1) * 32 + soff_sw,
                     Vs + (j >> 1) * 4096 + (j & 1) * 2048 + tid * 8);

        // K(kt) ready (retire everything except the 4 V loads just issued)
        asm volatile("s_waitcnt vmcnt(4)" ::: "memory");
        __builtin_amdgcn_s_barrier();
        __builtin_amdgcn_sched_barrier(0);

        // S^T = K Q^T : wave quadrant [32 c][64 q], 32 MFMAs, 8 LDS reads
        const f16* Kb = &Ks[kt & 1][0];
        f32x4 s[2][4];
#pragma unroll
        for (int mt = 0; mt < 2; ++mt)
#pragma unroll
            for (int nt = 0; nt < 4; ++nt)
                s[mt][nt] = (f32x4){0.f, 0.f, 0.f, 0.f};
        __builtin_amdgcn_s_setprio(1);
#pragma unroll
        for (int kc = 0; kc < 4; ++kc) {
            f16x8 kf0 = *(const f16x8*)&Kb[kc * 2048 + (wc * 32 + ln) * 32 + koff];
            f16x8 kf1 = *(const f16x8*)&Kb[kc * 2048 + (wc * 32 + 16 + ln) * 32 + koff];
#pragma unroll
            for (int nt = 0; nt < 4; ++nt) {
                s[0][nt] = __builtin_amdgcn_mfma_f32_16x16x32_f16(kf0, qf[nt][kc], s[0][nt], 0, 0, 0);
                s[1][nt] = __builtin_amdgcn_mfma_f32_16x16x32_f16(kf1, qf[nt][kc], s[1][nt], 0, 0, 0);
            }
        }
        __builtin_amdgcn_s_setprio(0);

        // issue K(kt+1) into the OTHER K buffer (no WAR with this tile)
        if (kt + 1 < S_LEN / 64) {
#pragma unroll
            for (int j = 0; j < 4; ++j)
                gl2lds16(Kgb + (size_t)((kt + 1) * 64 + srow) * DK + j * 32 + soff_sw,
                         &Ks[(kt + 1) & 1][j * 2048 + tid * 8]);
        }

        // exp (no max-sub), in-lane l partials, swizzled vectorized P write
#pragma unroll
        for (int mt = 0; mt < 2; ++mt) {
#pragma unroll
            for (int nt = 0; nt < 4; ++nt) {
                const float p0 = __expf(s[mt][nt][0]);
                const float p1 = __expf(s[mt][nt][1]);
                const float p2 = __expf(s[mt][nt][2]);
                const float p3 = __expf(s[mt][nt][3]);
                lp[nt] += (p0 + p1) + (p2 + p3);
                f16x4 pk;
                pk[0] = (f16)p0; pk[1] = (f16)p1; pk[2] = (f16)p2; pk[3] = (f16)p3;
                const int pchunk = ((mt * 2 + (quad >> 1)) ^ ((ln >> 1) & 3)) * 8
                                   + (quad & 1) * 4;
                *(f16x4*)&Ps[wc * 4096 + (wq * 64 + nt * 16 + ln) * 32 + pchunk] = pk;
            }
        }

        // V(kt) ready (K(kt+1) stays in flight); P visible after lgkm0+bar
        if (kt + 1 < S_LEN / 64) asm volatile("s_waitcnt vmcnt(4)" ::: "memory");
        else                     asm volatile("s_waitcnt vmcnt(0)" ::: "memory");
        asm volatile("s_waitcnt lgkmcnt(0)" ::: "memory");
        __builtin_amdgcn_s_barrier();
        __builtin_amdgcn_sched_barrier(0);

        // O += P V : wave quadrant [64 q][64 d], 32 MFMAs, 16 LDS reads
        __builtin_amdgcn_s_setprio(1);
#pragma unroll
        for (int cc = 0; cc < 2; ++cc) {
            f16x8 pf[4];
#pragma unroll
            for (int mtq = 0; mtq < 4; ++mtq)
                pf[mtq] = *(const f16x8*)&Ps[cc * 4096 + (wq * 64 + mtq * 16 + ln) * 32 + koff];
#pragma unroll
            for (int ntd = 0; ntd < 4; ++ntd) {
                f16x8 vf = *(const f16x8*)&Vs[cc * 4096 + (wc * 64 + ntd * 16 + ln) * 32 + koff];
#pragma unroll
                for (int mtq = 0; mtq < 4; ++mtq)
                    o[mtq][ntd] = __builtin_amdgcn_mfma_f32_16x16x32_f16(
                        pf[mtq], vf, o[mtq][ntd], 0, 0, 0);
            }
        }
        __builtin_amdgcn_s_setprio(0);
    }

    // finalize l: reduce over quads (c-spread), publish per (wc, q)
#pragma unroll
    for (int nt = 0; nt < 4; ++nt) {
        float v = lp[nt];
        v += __shfl_xor(v, 16, 64);
        v += __shfl_xor(v, 32, 64);
        lp[nt] = v;
    }
    __syncthreads();   // all PV reads done before l_buf aliases nothing; safe full sync
    if (quad == 0) {
#pragma unroll
        for (int nt = 0; nt < 4; ++nt)
            l_buf[wc * 128 + wq * 64 + nt * 16 + ln] = lp[nt];
    }
    __syncthreads();

    // epilogue: AO[b][s][h*DK + d] = o / l
    const int b = bh >> 4;
    const int h = bh & (NHEADS - 1);
#pragma unroll
    for (int mtq = 0; mtq < 4; ++mtq) {
#pragma unroll
        for (int reg = 0; reg < 4; ++reg) {
            const int ql = wq * 64 + mtq * 16 + quad * 4 + reg;
            const float inv = 1.0f / (l_buf[ql] + l_buf[128 + ql]);
            f16* dst = AO + ((size_t)b * S_LEN + q0 + ql) * DMODEL + h * DK + wc * 64;
#pragma unroll
            for (int ntd = 0; ntd < 4; ++ntd)
                dst[ntd * 16 + ln] = (f16)(o[mtq][ntd][reg] * inv);
        }
    }
}

// ---------------------------------------------------------------------------
// Buffer plan (race-free, r2 lesson): Kh/VT live in d_out (dead until
// out_gemm, which runs after flash and fully overwrites it). AOh aliases c_v
// (cross-launch only). No output of any launch aliases a same-launch input.
// ---------------------------------------------------------------------------
extern "C" void kernel_launch(void* const* d_in, const int* in_sizes, int n_in,
                              void* d_out, int out_size, void* d_ws, size_t ws_size,
                              hipStream_t stream)
{
    (void)in_sizes; (void)n_in; (void)out_size; (void)ws_size;
    const float* query = (const float*)d_in[0];
    const float* key_  = (const float*)d_in[1];
    const float* value = (const float*)d_in[2];
    const float* w_q = (const float*)d_in[3];
    const float* b_q = (const float*)d_in[4];
    const float* w_k = (const float*)d_in[5];
    const float* b_k = (const float*)d_in[6];
    const float* w_v = (const float*)d_in[7];
    const float* b_v = (const float*)d_in[8];
    const float* w_o = (const float*)d_in[9];
    const float* b_o = (const float*)d_in[10];
    const float* s_alpha = (const float*)d_in[11];
    const float* s_beta  = (const float*)d_in[12];
    float* out = (float*)d_out;

    const size_t T = (size_t)MROWS * DMODEL;    // 8,388,608
    const size_t Wn = (size_t)DMODEL * DMODEL;  // 4,194,304
    f16* base = (f16*)d_ws;
    f16* c_q = base;
    f16* c_k = base + T;
    f16* c_v = base + 2 * T;      // later reused as AOh (cross-launch, safe)
    f16* Qh  = base + 3 * T;
    f16* wq16 = base + 4 * T;
    f16* wk16 = wq16 + Wn;
    f16* wv16 = wk16 + Wn;
    f16* wo16 = wv16 + Wn;
    f16* Kh  = (f16*)d_out;       // 16MB: first half of d_out
    f16* VT  = Kh + T;            // 16MB: second half of d_out
    f16* AOh = c_v;

    cvt_all<<<dim3(10240), dim3(256), 0, stream>>>(
        query, key_, value, w_q, w_k, w_v, w_o,
        c_q, c_k, c_v, wq16, wk16, wv16, wo16);

    dim3 qkv_grid(DMODEL / 128, MROWS / 128, 3);  // (16, 32, 3) = 1536 blocks
    qkv_gemm<<<qkv_grid, dim3(256), 0, stream>>>(c_q, c_k, c_v, wq16, wk16, wv16,
                                                 b_q, b_k, b_v, Qh, Kh, VT,
                                                 s_alpha, s_beta);

    dim3 flash_grid(S_LEN / 128, 2 * NHEADS);     // (16, 32)
    flash_v6<<<flash_grid, dim3(256), 0, stream>>>(Qh, Kh, VT, AOh);

    dim3 out_grid(DMODEL / 128, MROWS / 128);     // (16, 32)
    out_gemm<<<out_grid, dim3(256), 0, stream>>>(AOh, wo16, b_o, out);
}

// Round 7
// 446.200 us; speedup vs baseline: 1.1607x; 1.0317x over previous
//
#include <hip/hip_runtime.h>
#include <cstdint>

// FracAttention: B=2, S=2048, D_MODEL=2048, H=16, DK=128
#define S_LEN   2048
#define DMODEL  2048
#define NHEADS  16
#define DK      128
#define MROWS   4096   // B*S

typedef _Float16 f16;
using f16x8 = __attribute__((ext_vector_type(8))) _Float16;
using f16x4 = __attribute__((ext_vector_type(4))) _Float16;
using f32x4 = __attribute__((ext_vector_type(4))) float;

typedef const __attribute__((address_space(1))) unsigned int gu32;
typedef __attribute__((address_space(3))) unsigned int lu32;

__device__ __forceinline__ void gl2lds16(const void* g, void* l) {
    // async global->LDS, 16 B per lane; LDS dest = wave-uniform base + lane*16
    __builtin_amdgcn_global_load_lds((gu32*)g, (lu32*)l, 16, 0, 0);
}

// ---------------------------------------------------------------------------
// fp32 -> fp16 convert. 4 float4 per thread (64 B/lane), 10240 blocks.
// ---------------------------------------------------------------------------
__global__ __launch_bounds__(256) void cvt_all(
    const float* __restrict__ q, const float* __restrict__ k,
    const float* __restrict__ v, const float* __restrict__ wq,
    const float* __restrict__ wk, const float* __restrict__ wv,
    const float* __restrict__ wo,
    f16* cq, f16* ck, f16* cv, f16* cwq, f16* cwk, f16* cwv, f16* cwo)
{
    const int b = blockIdx.x;
    const float* src; f16* dst; int base;
    if      (b <  2048) { src = q;  dst = cq;  base = b; }
    else if (b <  4096) { src = k;  dst = ck;  base = b - 2048; }
    else if (b <  6144) { src = v;  dst = cv;  base = b - 4096; }
    else if (b <  7168) { src = wq; dst = cwq; base = b - 6144; }
    else if (b <  8192) { src = wk; dst = cwk; base = b - 7168; }
    else if (b <  9216) { src = wv; dst = cwv; base = b - 8192; }
    else                { src = wo; dst = cwo; base = b - 9216; }
    const int i = base * 1024 + threadIdx.x;
#pragma unroll
    for (int u = 0; u < 4; ++u) {
        float4 x = ((const float4*)src)[i + u * 256];
        f16x4 o; o[0] = (f16)x.x; o[1] = (f16)x.y; o[2] = (f16)x.z; o[3] = (f16)x.w;
        ((f16x4*)dst)[i + u * 256] = o;
    }
}

// ---------------------------------------------------------------------------
// fp16 MFMA GEMM core: C[M][N] = A[M][K] @ W[N][K]^T + bias
// r0 measured-best structure (128x128 tile, 256 thr, 2x2 waves, 2 barriers
// per K-tile, gl2lds staging, high occupancy) with ONE change: BK 32 -> 64.
// Rationale: latency-bound at the per-tile vmcnt(0) drain; BK=64 doubles
// MFMA per drain (32/wave, ~156 cy) and halves drain count; LDS 32 KB
// keeps 5 blocks/CU (m132's BK=128 failure was the 64 KB occupancy cliff).
// Rows are now 128 B -> mandatory 8-chunk XOR swizzle (G4 16-way case):
// staging source chunk (t&7)^((t>>3)&7) [LDS dest linear, m104], read chunk
// (kq*4+quad)^(ln&7) -- per-16-lane phase: 8 distinct 16B slots x 2 lanes
// = conflict-free (same involution family measured 0 conflicts in r1/r4).
// mode 0: fp32 out [M][N]
// mode 1: f16 out head-permuted  [B,H,S,DK]             (K)
// mode 2: f16 out head-permuted + transposed [B,H,DK,S] (V -> VT)
// mode 3: f16 out head-permuted, scaled by sa[h]/max(sb[h],1)  (Q)
// ---------------------------------------------------------------------------
__device__ __forceinline__ void gemm_core(
    const f16* __restrict__ A, const f16* __restrict__ W,
    const float* __restrict__ bias, void* __restrict__ Cout,
    int mode, const float* __restrict__ sa, const float* __restrict__ sb)
{
    __shared__ f16 As[128 * 64];   // [m][64], 16 KB
    __shared__ f16 Bs[128 * 64];   // [n][64], 16 KB

    const int tid = threadIdx.x;
    const int bm = blockIdx.y * 128;
    const int bn = blockIdx.x * 128;
    const int wid = tid >> 6;
    const int ln = tid & 15;
    const int quad = (tid & 63) >> 4;
    const int wm = (wid >> 1) * 64;
    const int wn = (wid & 1) * 64;
    const int K = DMODEL, N = DMODEL;

    f32x4 acc[4][4];
#pragma unroll
    for (int i = 0; i < 4; ++i)
#pragma unroll
        for (int j = 0; j < 4; ++j)
            acc[i][j] = (f32x4){0.f, 0.f, 0.f, 0.f};

    // staging: thread t -> row (t>>3)+u*32, logical chunk (t&7) placed at
    // physical chunk (t&7); source pre-swizzled by row key (t>>3)&7.
    const int srow = tid >> 3;                                  // 0..31
    const int schk = ((tid & 7) ^ ((tid >> 3) & 7)) * 8;        // f16 offset
    const f16* ga = A + (size_t)(bm + srow) * K + schk;
    const f16* gb = W + (size_t)(bn + srow) * K + schk;

    for (int k0 = 0; k0 < K; k0 += 64) {
        __syncthreads();
#pragma unroll
        for (int u = 0; u < 4; ++u)
            gl2lds16(ga + k0 + (size_t)(u * 32) * K, As + u * 2048 + tid * 8);
#pragma unroll
        for (int u = 0; u < 4; ++u)
            gl2lds16(gb + k0 + (size_t)(u * 32) * K, Bs + u * 2048 + tid * 8);
        __syncthreads();

#pragma unroll
        for (int kq = 0; kq < 2; ++kq) {
            f16x8 af[4], bf[4];
            const int rc = ((kq * 4 + quad) ^ (ln & 7)) * 8;    // swizzled chunk
#pragma unroll
            for (int i = 0; i < 4; ++i)
                af[i] = *(const f16x8*)&As[(wm + i * 16 + ln) * 64 + rc];
#pragma unroll
            for (int j = 0; j < 4; ++j)
                bf[j] = *(const f16x8*)&Bs[(wn + j * 16 + ln) * 64 + rc];
#pragma unroll
            for (int i = 0; i < 4; ++i)
#pragma unroll
                for (int j = 0; j < 4; ++j)
                    acc[i][j] = __builtin_amdgcn_mfma_f32_16x16x32_f16(
                        af[i], bf[j], acc[i][j], 0, 0, 0);
        }
    }

    // epilogue: C/D layout col=lane&15, row=quad*4+reg
#pragma unroll
    for (int j = 0; j < 4; ++j) {
        const int n = bn + wn + j * 16 + ln;
        const float bn_ = bias[n];
        const int h = n >> 7;           // n / DK
        const int d = n & (DK - 1);
        float scq = 1.0f;
        if (mode == 3) scq = sa[h] / fmaxf(sb[h], 1.0f);
#pragma unroll
        for (int i = 0; i < 4; ++i) {
#pragma unroll
            for (int reg = 0; reg < 4; ++reg) {
                const int m = bm + wm + i * 16 + quad * 4 + reg;
                float v = acc[i][j][reg] + bn_;
                if (mode == 0) {
                    ((float*)Cout)[(size_t)m * N + n] = v;
                } else {
                    const int bb = m >> 11;          // / S_LEN
                    const int ss = m & (S_LEN - 1);
                    size_t idx;
                    if (mode == 2)
                        idx = (((size_t)(bb * NHEADS + h) * DK + d) * S_LEN + ss);
                    else
                        idx = (((size_t)(bb * NHEADS + h) * S_LEN + ss) * DK + d);
                    if (mode == 3) v *= scq;
                    ((f16*)Cout)[idx] = (f16)v;
                }
            }
        }
    }
}

__global__ __launch_bounds__(256) void qkv_gemm(
    const f16* Aq, const f16* Ak, const f16* Av,
    const f16* Wq, const f16* Wk, const f16* Wv,
    const float* bq, const float* bk, const float* bv,
    f16* Oq, f16* Ok, f16* Ov, const float* sa, const float* sb)
{
    const int z = blockIdx.z;
    const f16* A = (z == 0) ? Aq : (z == 1) ? Ak : Av;
    const f16* W = (z == 0) ? Wq : (z == 1) ? Wk : Wv;
    const float* bias = (z == 0) ? bq : (z == 1) ? bk : bv;
    void* O = (z == 0) ? (void*)Oq : (z == 1) ? (void*)Ok : (void*)Ov;
    const int mode = (z == 0) ? 3 : (z == 1) ? 1 : 2;
    gemm_core(A, W, bias, O, mode, sa, sb);
}

__global__ __launch_bounds__(256) void out_gemm(
    const f16* A, const f16* W, const float* bias, float* O)
{
    gemm_core(A, W, bias, O, 0, nullptr, nullptr);
}

// ---------------------------------------------------------------------------
// Flash attention v6 (UNCHANGED from r6): K double-buffered + counted-vmcnt
// pipeline; T2 swizzles + setprio; XCD bh-chunk swizzle.
// ---------------------------------------------------------------------------
__global__ __launch_bounds__(256, 2) void flash_v6(
    const f16* __restrict__ Qg, const f16* __restrict__ Kg,
    const f16* __restrict__ VTg, f16* __restrict__ AO)
{
    __shared__ f16 Ks[2][4 * 64 * 32];  // dbuf: [kb][kc][c][32]  32 KB
    __shared__ f16 Vs[2 * 128 * 32];    // [cc][d][32]            16 KB
    __shared__ f16 Ps[2 * 128 * 32];    // [cc][q][32]            16 KB
    __shared__ float l_buf[2 * 128];    // [wc][q]                 1 KB

    const int tid = threadIdx.x;
    const int wid = tid >> 6;
    const int ln = tid & 15;
    const int quad = (tid & 63) >> 4;
    const int wq = wid & 1;
    const int wc = wid >> 1;

    // XCD chunk swizzle: 512 blocks, 64 consecutive per XCD.
    const int lin = blockIdx.x + (blockIdx.y << 4);
    const int swz = (lin & 7) * 64 + (lin >> 3);
    const int q0 = (swz & 15) * 128;
    const int bh = swz >> 4;

    const int koff = (quad ^ ((ln >> 1) & 3)) * 8;                 // read, b128
    const int soff_sw = ((tid & 3) ^ ((tid >> 3) & 3)) * 8;        // staging src

    f16x8 qf[4][4];
    const f16* Qbase = Qg + ((size_t)bh * S_LEN + q0 + wq * 64) * DK;
#pragma unroll
    for (int nt = 0; nt < 4; ++nt)
#pragma unroll
        for (int kc = 0; kc < 4; ++kc)
            qf[nt][kc] = *(const f16x8*)(Qbase + (size_t)(nt * 16 + ln) * DK
                                         + kc * 32 + quad * 8);

    f32x4 o[4][4];
    float lp[4] = {0.f, 0.f, 0.f, 0.f};
#pragma unroll
    for (int i = 0; i < 4; ++i)
#pragma unroll
        for (int j = 0; j < 4; ++j)
            o[i][j] = (f32x4){0.f, 0.f, 0.f, 0.f};

    const f16* Kgb = Kg + (size_t)bh * S_LEN * DK;
    const f16* Vgb = VTg + (size_t)bh * DK * S_LEN;
    const int srow = tid >> 2;

    // prologue: stage K(0) into Ks[0]
#pragma unroll
    for (int j = 0; j < 4; ++j)
        gl2lds16(Kgb + (size_t)(srow)*DK + j * 32 + soff_sw,
                 &Ks[0][j * 2048 + tid * 8]);

    for (int kt = 0; kt < S_LEN / 64; ++kt) {
        asm volatile("s_waitcnt lgkmcnt(0)" ::: "memory");
        __builtin_amdgcn_s_barrier();
        __builtin_amdgcn_sched_barrier(0);

        // issue V(kt)
#pragma unroll
        for (int j = 0; j < 4; ++j)
            gl2lds16(Vgb + (size_t)(srow + (j & 1) * 64) * S_LEN
                         + kt * 64 + (j >> 1) * 32 + soff_sw,
                     Vs + (j >> 1) * 4096 + (j & 1) * 2048 + tid * 8);

        // K(kt) ready (retire all but the 4 V loads just issued)
        asm volatile("s_waitcnt vmcnt(4)" ::: "memory");
        __builtin_amdgcn_s_barrier();
        __builtin_amdgcn_sched_barrier(0);

        const f16* Kb = &Ks[kt & 1][0];
        f32x4 s[2][4];
#pragma unroll
        for (int mt = 0; mt < 2; ++mt)
#pragma unroll
            for (int nt = 0; nt < 4; ++nt)
                s[mt][nt] = (f32x4){0.f, 0.f, 0.f, 0.f};
        __builtin_amdgcn_s_setprio(1);
#pragma unroll
        for (int kc = 0; kc < 4; ++kc) {
            f16x8 kf0 = *(const f16x8*)&Kb[kc * 2048 + (wc * 32 + ln) * 32 + koff];
            f16x8 kf1 = *(const f16x8*)&Kb[kc * 2048 + (wc * 32 + 16 + ln) * 32 + koff];
#pragma unroll
            for (int nt = 0; nt < 4; ++nt) {
                s[0][nt] = __builtin_amdgcn_mfma_f32_16x16x32_f16(kf0, qf[nt][kc], s[0][nt], 0, 0, 0);
                s[1][nt] = __builtin_amdgcn_mfma_f32_16x16x32_f16(kf1, qf[nt][kc], s[1][nt], 0, 0, 0);
            }
        }
        __builtin_amdgcn_s_setprio(0);

        // issue K(kt+1) into the OTHER K buffer
        if (kt + 1 < S_LEN / 64) {
#pragma unroll
            for (int j = 0; j < 4; ++j)
                gl2lds16(Kgb + (size_t)((kt + 1) * 64 + srow) * DK + j * 32 + soff_sw,
                         &Ks[(kt + 1) & 1][j * 2048 + tid * 8]);
        }

        // exp (no max-sub), in-lane l partials, swizzled vectorized P write
#pragma unroll
        for (int mt = 0; mt < 2; ++mt) {
#pragma unroll
            for (int nt = 0; nt < 4; ++nt) {
                const float p0 = __expf(s[mt][nt][0]);
                const float p1 = __expf(s[mt][nt][1]);
                const float p2 = __expf(s[mt][nt][2]);
                const float p3 = __expf(s[mt][nt][3]);
                lp[nt] += (p0 + p1) + (p2 + p3);
                f16x4 pk;
                pk[0] = (f16)p0; pk[1] = (f16)p1; pk[2] = (f16)p2; pk[3] = (f16)p3;
                const int pchunk = ((mt * 2 + (quad >> 1)) ^ ((ln >> 1) & 3)) * 8
                                   + (quad & 1) * 4;
                *(f16x4*)&Ps[wc * 4096 + (wq * 64 + nt * 16 + ln) * 32 + pchunk] = pk;
            }
        }

        // V(kt) ready (K(kt+1) stays in flight); P visible after lgkm0+bar
        if (kt + 1 < S_LEN / 64) asm volatile("s_waitcnt vmcnt(4)" ::: "memory");
        else                     asm volatile("s_waitcnt vmcnt(0)" ::: "memory");
        asm volatile("s_waitcnt lgkmcnt(0)" ::: "memory");
        __builtin_amdgcn_s_barrier();
        __builtin_amdgcn_sched_barrier(0);

        __builtin_amdgcn_s_setprio(1);
#pragma unroll
        for (int cc = 0; cc < 2; ++cc) {
            f16x8 pf[4];
#pragma unroll
            for (int mtq = 0; mtq < 4; ++mtq)
                pf[mtq] = *(const f16x8*)&Ps[cc * 4096 + (wq * 64 + mtq * 16 + ln) * 32 + koff];
#pragma unroll
            for (int ntd = 0; ntd < 4; ++ntd) {
                f16x8 vf = *(const f16x8*)&Vs[cc * 4096 + (wc * 64 + ntd * 16 + ln) * 32 + koff];
#pragma unroll
                for (int mtq = 0; mtq < 4; ++mtq)
                    o[mtq][ntd] = __builtin_amdgcn_mfma_f32_16x16x32_f16(
                        pf[mtq], vf, o[mtq][ntd], 0, 0, 0);
            }
        }
        __builtin_amdgcn_s_setprio(0);
    }

    // finalize l: reduce over quads (c-spread), publish per (wc, q)
#pragma unroll
    for (int nt = 0; nt < 4; ++nt) {
        float v = lp[nt];
        v += __shfl_xor(v, 16, 64);
        v += __shfl_xor(v, 32, 64);
        lp[nt] = v;
    }
    __syncthreads();
    if (quad == 0) {
#pragma unroll
        for (int nt = 0; nt < 4; ++nt)
            l_buf[wc * 128 + wq * 64 + nt * 16 + ln] = lp[nt];
    }
    __syncthreads();

    // epilogue: AO[b][s][h*DK + d] = o / l
    const int b = bh >> 4;
    const int h = bh & (NHEADS - 1);
#pragma unroll
    for (int mtq = 0; mtq < 4; ++mtq) {
#pragma unroll
        for (int reg = 0; reg < 4; ++reg) {
            const int ql = wq * 64 + mtq * 16 + quad * 4 + reg;
            const float inv = 1.0f / (l_buf[ql] + l_buf[128 + ql]);
            f16* dst = AO + ((size_t)b * S_LEN + q0 + ql) * DMODEL + h * DK + wc * 64;
#pragma unroll
            for (int ntd = 0; ntd < 4; ++ntd)
                dst[ntd * 16 + ln] = (f16)(o[mtq][ntd][reg] * inv);
        }
    }
}

// ---------------------------------------------------------------------------
// Buffer plan (race-free, r2 lesson): Kh/VT live in d_out (dead until
// out_gemm, which runs after flash and fully overwrites it). AOh aliases c_v
// (cross-launch only). No output of any launch aliases a same-launch input.
// ---------------------------------------------------------------------------
extern "C" void kernel_launch(void* const* d_in, const int* in_sizes, int n_in,
                              void* d_out, int out_size, void* d_ws, size_t ws_size,
                              hipStream_t stream)
{
    (void)in_sizes; (void)n_in; (void)out_size; (void)ws_size;
    const float* query = (const float*)d_in[0];
    const float* key_  = (const float*)d_in[1];
    const float* value = (const float*)d_in[2];
    const float* w_q = (const float*)d_in[3];
    const float* b_q = (const float*)d_in[4];
    const float* w_k = (const float*)d_in[5];
    const float* b_k = (const float*)d_in[6];
    const float* w_v = (const float*)d_in[7];
    const float* b_v = (const float*)d_in[8];
    const float* w_o = (const float*)d_in[9];
    const float* b_o = (const float*)d_in[10];
    const float* s_alpha = (const float*)d_in[11];
    const float* s_beta  = (const float*)d_in[12];
    float* out = (float*)d_out;

    const size_t T = (size_t)MROWS * DMODEL;    // 8,388,608
    const size_t Wn = (size_t)DMODEL * DMODEL;  // 4,194,304
    f16* base = (f16*)d_ws;
    f16* c_q = base;
    f16* c_k = base + T;
    f16* c_v = base + 2 * T;      // later reused as AOh (cross-launch, safe)
    f16* Qh  = base + 3 * T;
    f16* wq16 = base + 4 * T;
    f16* wk16 = wq16 + Wn;
    f16* wv16 = wk16 + Wn;
    f16* wo16 = wv16 + Wn;
    f16* Kh  = (f16*)d_out;       // 16MB: first half of d_out
    f16* VT  = Kh + T;            // 16MB: second half of d_out
    f16* AOh = c_v;

    cvt_all<<<dim3(10240), dim3(256), 0, stream>>>(
        query, key_, value, w_q, w_k, w_v, w_o,
        c_q, c_k, c_v, wq16, wk16, wv16, wo16);

    dim3 qkv_grid(DMODEL / 128, MROWS / 128, 3);  // (16, 32, 3) = 1536 blocks
    qkv_gemm<<<qkv_grid, dim3(256), 0, stream>>>(c_q, c_k, c_v, wq16, wk16, wv16,
                                                 b_q, b_k, b_v, Qh, Kh, VT,
                                                 s_alpha, s_beta);

    dim3 flash_grid(S_LEN / 128, 2 * NHEADS);     // (16, 32)
    flash_v6<<<flash_grid, dim3(256), 0, stream>>>(Qh, Kh, VT, AOh);

    dim3 out_grid(DMODEL / 128, MROWS / 128);     // (16, 32)
    out_gemm<<<out_grid, dim3(256), 0, stream>>>(AOh, wo16, b_o, out);
}